// Round 14
// baseline (1070.038 us; speedup 1.0000x reference)
//
#include <hip/hip_runtime.h>
#include <math.h>

#define NUM_LEVELS 16
#define LOG2_T 21
#define TABLE_SIZE (1u << LOG2_T)
#define HASH_MASK (TABLE_SIZE - 1u)
#define N_POINTS 262144
#define GRID_P1 1024           // 128 slices x 8 xcd-slots
#define PTS_PER_BLOCK 2048     // 8 pts/thread x 256 threads
#define CAP 2560               // queue capacity: mean 2048 + 12 sigma
#define PX 73856093u
#define PY 19349663u
#define PZ 83492791u

struct Args { float r[NUM_LEVELS]; int l2nc[NUM_LEVELS]; };

// ---- phase 1: XCD-pinned levels, L2 chunks, LDS-binned all-useful gathers --
__global__ __launch_bounds__(256) void hash_embed_phase1_v14(
    const float* __restrict__ x,
    const float* __restrict__ tables,
    float2* __restrict__ wsbuf,       // [NUM_LEVELS][N_POINTS]
    Args args)
{
    __shared__ uint32_t qmeta[CAP];           // idx(21) | pt-in-block(11)
    __shared__ float    qw[CAP];              // trilinear weight
    __shared__ float    acc[PTS_PER_BLOCK*2]; // per-point float2 accumulators
    __shared__ int      cnt;

    const int tid = threadIdx.x;
    const int bid = blockIdx.x;
    const int slot = bid & 7;          // dispatch-order XCD heuristic (perf-only)
    const int slice = bid >> 3;        // 0..127
    const int base = slice * PTS_PER_BLOCK + tid;
    const int lane = tid & 63;
    float2* accv = (float2*)acc;

    // persistent: clamped normalized coords (x read once for both levels)
    float nxx[8], nyy[8], nzz[8];
    #pragma unroll
    for (int p = 0; p < 8; ++p) {
        const int n = base + p * 256;
        nxx[p] = fminf(fmaxf((x[n*3+0] + 2.0f) * 0.25f, 0.0f), 1.0f);
        nyy[p] = fminf(fmaxf((x[n*3+1] + 2.0f) * 0.25f, 0.0f), 1.0f);
        nzz[p] = fminf(fmaxf((x[n*3+2] + 2.0f) * 0.25f, 0.0f), 1.0f);
    }

    #pragma unroll 1
    for (int li = 0; li < 2; ++li) {
        const int lv = li ? (15 - slot) : slot;
        const float r = args.r[lv];
        const int l2nc = args.l2nc[lv];
        const int shift = LOG2_T - l2nc;
        const int nc = 1 << l2nc;
        const float* __restrict__ tab =
            tables + (size_t)lv * ((size_t)TABLE_SIZE * 2);

        // per-level cached per-point hash bases + fractions (6 regs x 8 pts)
        uint32_t hx[8], hy[8], hz[8];
        float qx[8], qy[8], qz[8];
        #pragma unroll
        for (int p = 0; p < 8; ++p) {
            const float sx = nxx[p]*r, sy = nyy[p]*r, sz = nzz[p]*r;
            const float fx = floorf(sx), fy = floorf(sy), fz = floorf(sz);
            qx[p] = sx - fx; qy[p] = sy - fy; qz[p] = sz - fz;
            hx[p] = (uint32_t)(int)fx * PX;
            hy[p] = (uint32_t)(int)fy * PY;
            hz[p] = (uint32_t)(int)fz * PZ;
        }

        if (l2nc == 0) {
            // coarse L2-resident level: direct register path
            #pragma unroll
            for (int p = 0; p < 8; ++p) {
                const uint32_t X0 = hx[p], Y0 = hy[p], Z0 = hz[p];
                const uint32_t X1 = X0 + PX, Y1 = Y0 + PY, Z1 = Z0 + PZ;
                const float vqx = qx[p], vqy = qy[p], vqz = qz[p];
                const float ax = 1.0f - vqx, ay = 1.0f - vqy, az = 1.0f - vqz;
                float a0 = 0.0f, a1 = 0.0f;
                #pragma unroll
                for (int i = 0; i < 8; ++i) {
                    const uint32_t idx = (((i&4)?X1:X0) ^ ((i&2)?Y1:Y0)
                                        ^ ((i&1)?Z1:Z0)) & HASH_MASK;
                    const float2 e = *(const float2*)(tab + (size_t)idx * 2);
                    const float w = (((i&4)?vqx:ax) * ((i&2)?vqy:ay)) * ((i&1)?vqz:az);
                    a0 = fmaf(w, e.x, a0);
                    a1 = fmaf(w, e.y, a1);
                }
                wsbuf[(size_t)lv*N_POINTS + base + p*256] = make_float2(a0, a1);
            }
        } else {
            // binned path: zero per-point accumulators
            for (int e = tid; e < PTS_PER_BLOCK; e += 256)
                accv[e] = make_float2(0.0f, 0.0f);

            #pragma unroll 1
            for (int c = 0; c < nc; ++c) {
                if (tid == 0) cnt = 0;
                __syncthreads();

                // ---- scan & bin: wave-ballot compaction into LDS queue ----
                #pragma unroll
                for (int p = 0; p < 8; ++p) {
                    const uint32_t X0 = hx[p], Y0 = hy[p], Z0 = hz[p];
                    const uint32_t X1 = X0 + PX, Y1 = Y0 + PY, Z1 = Z0 + PZ;
                    const float vqx = qx[p], vqy = qy[p], vqz = qz[p];
                    const float ax = 1.0f - vqx, ay = 1.0f - vqy, az = 1.0f - vqz;
                    const uint32_t ptid = (uint32_t)(tid + p*256);
                    #pragma unroll
                    for (int i = 0; i < 8; ++i) {
                        const uint32_t idx = (((i&4)?X1:X0) ^ ((i&2)?Y1:Y0)
                                            ^ ((i&1)?Z1:Z0)) & HASH_MASK;
                        const bool m = (idx >> shift) == (uint32_t)c;
                        const unsigned long long mk = __ballot(m);
                        int bw = 0;
                        if (lane == 0 && mk) bw = atomicAdd(&cnt, (int)__popcll(mk));
                        bw = __shfl(bw, 0);
                        if (m) {
                            const int off = bw +
                                (int)__popcll(mk & ((1ull << lane) - 1ull));
                            const float w = (((i&4)?vqx:ax) * ((i&2)?vqy:ay))
                                          * ((i&1)?vqz:az);
                            if (off < CAP) {
                                qmeta[off] = idx | (ptid << 21);
                                qw[off] = w;
                            } else {
                                // overflow fallback (statistically ~never)
                                const float2 e = *(const float2*)(tab + (size_t)idx*2);
                                atomicAdd(&acc[2*ptid],   w * e.x);
                                atomicAdd(&acc[2*ptid+1], w * e.y);
                            }
                        }
                    }
                }
                __syncthreads();

                // ---- process: all-useful coalesced-issue gathers ----------
                const int K = min(cnt, CAP);
                for (int e = tid; e < K; e += 256) {
                    const uint32_t mt = qmeta[e];
                    const float w = qw[e];
                    const uint32_t idx = mt & HASH_MASK;
                    const int pt = (int)(mt >> 21);
                    const float2 em = *(const float2*)(tab + (size_t)idx * 2);
                    atomicAdd(&acc[2*pt],   w * em.x);
                    atomicAdd(&acc[2*pt+1], w * em.y);
                }
                __syncthreads();
            }

            // write out this level's results
            #pragma unroll
            for (int p = 0; p < 8; ++p) {
                const int ptid = tid + p*256;
                wsbuf[(size_t)lv*N_POINTS + base + p*256] = accv[ptid];
            }
            __syncthreads();   // protect acc until all reads done
        }
    }
}

// ---- phase 2: transpose ws[l][n] -> out[n][l] ------------------------------
__global__ __launch_bounds__(256) void hash_embed_phase2(
    const float2* __restrict__ ws,
    float2* __restrict__ out)
{
    __shared__ float2 tile[64][NUM_LEVELS + 1];
    const int n0 = blockIdx.x * 64;
    const int t = threadIdx.x;
    #pragma unroll
    for (int k = 0; k < 4; ++k) {
        const int e = k * 256 + t;
        const int l = e >> 6;
        const int j = e & 63;
        tile[j][l] = ws[(size_t)l * N_POINTS + n0 + j];
    }
    __syncthreads();
    #pragma unroll
    for (int k = 0; k < 4; ++k) {
        const int e = k * 256 + t;
        const int nl = e >> 4;
        const int l = e & 15;
        out[(size_t)(n0 + nl) * NUM_LEVELS + l] = tile[nl][l];
    }
}

// ---- fallback (R1-proven): interleaved levels, direct out ------------------
__global__ __launch_bounds__(256) void hash_embed_direct(
    const float* __restrict__ x,
    const float* __restrict__ tables,
    float* __restrict__ out,
    Args args)
{
    const int t = blockIdx.x * blockDim.x + threadIdx.x;
    const int n = t >> 4;
    const int l = t & 15;
    if (n >= N_POINTS) return;

    const float px = x[n * 3 + 0];
    const float py = x[n * 3 + 1];
    const float pz = x[n * 3 + 2];
    const float nx = fminf(fmaxf((px + 2.0f) * 0.25f, 0.0f), 1.0f);
    const float ny = fminf(fmaxf((py + 2.0f) * 0.25f, 0.0f), 1.0f);
    const float nz = fminf(fmaxf((pz + 2.0f) * 0.25f, 0.0f), 1.0f);

    const float r = args.r[l];
    const float sx = nx * r, sy = ny * r, sz = nz * r;
    const float fx = floorf(sx), fy = floorf(sy), fz = floorf(sz);
    const float wxv = sx - fx, wyv = sy - fy, wzv = sz - fz;

    const uint32_t hx0 = (uint32_t)(int)fx * PX;
    const uint32_t hy0 = (uint32_t)(int)fy * PY;
    const uint32_t hz0 = (uint32_t)(int)fz * PZ;
    const uint32_t hx1 = hx0 + PX, hy1 = hy0 + PY, hz1 = hz0 + PZ;

    const float ax = 1.0f - wxv, ay = 1.0f - wyv, az = 1.0f - wzv;
    const float* __restrict__ tab = tables + (size_t)l * ((size_t)TABLE_SIZE * 2);

    float f0 = 0.0f, f1 = 0.0f;
    #pragma unroll
    for (int c = 0; c < 8; ++c) {
        const uint32_t hh = ((c & 4) ? hx1 : hx0) ^ ((c & 2) ? hy1 : hy0)
                          ^ ((c & 1) ? hz1 : hz0);
        const uint32_t idx = hh & HASH_MASK;
        const float2 emb = *reinterpret_cast<const float2*>(tab + (size_t)idx * 2);
        const float w = (((c & 4) ? wxv : ax) * ((c & 2) ? wyv : ay)) * ((c & 1) ? wzv : az);
        f0 = fmaf(w, emb.x, f0);
        f1 = fmaf(w, emb.y, f1);
    }
    float2* o = reinterpret_cast<float2*>(out + (size_t)n * (NUM_LEVELS * 2) + l * 2);
    *o = make_float2(f0, f1);
}

extern "C" void kernel_launch(void* const* d_in, const int* in_sizes, int n_in,
                              void* d_out, int out_size, void* d_ws, size_t ws_size,
                              hipStream_t stream) {
    const float* x      = (const float*)d_in[0];
    const float* tables = (const float*)d_in[1];
    float* out          = (float*)d_out;

    Args args;
    const double b = exp((log(2048.0) - log(16.0)) / 15.0);
    for (int i = 0; i < NUM_LEVELS; ++i) {
        const double ri = floor(16.0 * pow(b, (double)i));
        args.r[i] = (float)ri;
        // accessed-footprint model: E distinct corners hash-spread over 2^21
        // slots, 8 entries per 64B line
        double E = (ri + 1.0) * (ri + 1.0) * (ri + 1.0);
        if (E > 1.8e6) E = 1.8e6;
        const double lines = 262144.0 * (1.0 - exp(-8.0 * E / 2097152.0));
        const double bytes = lines * 64.0;
        // <=2.5 MB: direct path (L2-resident). Else: 8 chunks, binned.
        args.l2nc[i] = (bytes <= 2.5e6) ? 0 : 3;
    }

    const size_t ws_needed = (size_t)NUM_LEVELS * N_POINTS * sizeof(float2); // 32 MB
    if (ws_size >= ws_needed) {
        float2* wsbuf = (float2*)d_ws;
        hipLaunchKernelGGL(hash_embed_phase1_v14, dim3(GRID_P1), dim3(256),
                           0, stream, x, tables, wsbuf, args);
        hipLaunchKernelGGL(hash_embed_phase2, dim3(N_POINTS / 64), dim3(256),
                           0, stream, wsbuf, (float2*)out);
    } else {
        const int total = N_POINTS * NUM_LEVELS;
        hipLaunchKernelGGL(hash_embed_direct, dim3((total + 255) / 256), dim3(256),
                           0, stream, x, tables, out, args);
    }
}

// Round 15
// 461.642 us; speedup vs baseline: 2.3179x; 2.3179x over previous
//
#include <hip/hip_runtime.h>
#include <math.h>
#include <string.h>

#define NUM_LEVELS 16
#define LOG2_T 21
#define TABLE_SIZE (1u << LOG2_T)
#define HASH_MASK (TABLE_SIZE - 1u)
#define N_POINTS 262144
#define GRID_P1 1024           // 128 slices x 8 xcd-slots
#define PTS_PER_BLOCK 2048     // 8 pts/thread x 256 threads
#define MAX_UNITS 128
#define PX 73856093u
#define PY 19349663u
#define PZ 83492791u

struct Args {
    float r[NUM_LEVELS];
    uint32_t ncMul[NUM_LEVELS];
    uint32_t units[MAX_UNITS];     // lv<<27 | c<<24 | chunkStartEntry(24b)
    int slotStart[9];
};

// two-level paste so trailing digit doesn't fuse with ".x" into one pp-token
#define CAT3_(a, b, c) a##b##c
#define TREG(SET, i) CAT3_(t, SET, i)

// Corner load: match test via cid = (idx*nc)>>21 (non-pow2 chunks ok).
// Non-matching lanes load the chunk-start line (uniform -> 1 coalesced line)
// with weight forced to 0.
#define CORNER(SET, i)                                                        \
    {                                                                         \
        const uint32_t h = (((i) & 4) ? X1 : X0) ^ (((i) & 2) ? Y1 : Y0)      \
                         ^ (((i) & 1) ? Z1 : Z0);                             \
        const uint32_t idx = h & HASH_MASK;                                   \
        const uint32_t cid = (idx * ncMul) >> 21;                             \
        const bool m = (cid == cc);                                           \
        const uint32_t off = m ? (idx << 3) : dummy_off;                      \
        wc##SET[i] = m ? (((((i) & 4) ? qx : axq) * (((i) & 2) ? qy : ayq))   \
                          * (((i) & 1) ? qz : azq))                           \
                       : 0.0f;                                                \
        asm volatile("global_load_dwordx2 %0, %1, %2"                         \
                     : "=v"(TREG(SET, i)) : "v"(off), "s"(tab));              \
    }

#define ISSUE(SET, p)                                                         \
    {                                                                         \
        const float sx = nxx[p] * r, sy = nyy[p] * r, sz = nzz[p] * r;        \
        const float fx = floorf(sx), fy = floorf(sy), fz = floorf(sz);        \
        const float qx = sx - fx, qy = sy - fy, qz = sz - fz;                 \
        const float axq = 1.0f - qx, ayq = 1.0f - qy, azq = 1.0f - qz;        \
        const uint32_t X0 = (uint32_t)(int)fx * PX;                           \
        const uint32_t Y0 = (uint32_t)(int)fy * PY;                           \
        const uint32_t Z0 = (uint32_t)(int)fz * PZ;                           \
        const uint32_t X1 = X0 + PX, Y1 = Y0 + PY, Z1 = Z0 + PZ;              \
        CORNER(SET, 0) CORNER(SET, 1) CORNER(SET, 2) CORNER(SET, 3)           \
        CORNER(SET, 4) CORNER(SET, 5) CORNER(SET, 6) CORNER(SET, 7)           \
    }

#define WAIT(SET, CNT)                                                        \
    asm volatile("s_waitcnt vmcnt(" #CNT ")"                                  \
                 : "+v"(TREG(SET, 0)), "+v"(TREG(SET, 1)),                    \
                   "+v"(TREG(SET, 2)), "+v"(TREG(SET, 3)),                    \
                   "+v"(TREG(SET, 4)), "+v"(TREG(SET, 5)),                    \
                   "+v"(TREG(SET, 6)), "+v"(TREG(SET, 7)));

#define FMA2(SET, p, i)                                                       \
    a0[p] = fmaf(wc##SET[i], TREG(SET, i).x, a0[p]);                          \
    a1[p] = fmaf(wc##SET[i], TREG(SET, i).y, a1[p]);

#define FMA8(SET, p)                                                          \
    FMA2(SET, p, 0) FMA2(SET, p, 1) FMA2(SET, p, 2) FMA2(SET, p, 3)           \
    FMA2(SET, p, 4) FMA2(SET, p, 5) FMA2(SET, p, 6) FMA2(SET, p, 7)

// ---- phase 1: unit-balanced (level,chunk) schedule, atomic partial flushes -
__global__ __launch_bounds__(256) void hash_embed_phase1_v15(
    const float* __restrict__ x,
    const float* __restrict__ tables,
    float* __restrict__ wsbuf,        // [NUM_LEVELS][N_POINTS][2], pre-zeroed
    Args args)
{
    const int bid = blockIdx.x;
    const int slot = bid & 7;          // dispatch-order XCD heuristic (perf-only)
    const int slice = bid >> 3;        // 0..127
    const int base = slice * PTS_PER_BLOCK + threadIdx.x;

    // persistent: clamped normalized coords (x read once)
    float nxx[8], nyy[8], nzz[8];
    #pragma unroll
    for (int p = 0; p < 8; ++p) {
        const int n = base + p * 256;
        nxx[p] = fminf(fmaxf((x[n*3+0] + 2.0f) * 0.25f, 0.0f), 1.0f);
        nyy[p] = fminf(fmaxf((x[n*3+1] + 2.0f) * 0.25f, 0.0f), 1.0f);
        nzz[p] = fminf(fmaxf((x[n*3+2] + 2.0f) * 0.25f, 0.0f), 1.0f);
    }

    float a0[8], a1[8];
    int curLv = -1;

    const int ubeg = args.slotStart[slot];
    const int uend = args.slotStart[slot + 1];

    #pragma unroll 1
    for (int uu = ubeg; uu < uend; ++uu) {
        const uint32_t u = args.units[uu];
        const int lv = (int)(u >> 27);
        const uint32_t cc = (u >> 24) & 7u;
        const uint32_t dummy_off = (u & 0xFFFFFFu) << 3;

        if (lv != curLv) {
            if (curLv >= 0) {
                #pragma unroll
                for (int p = 0; p < 8; ++p) {
                    float* w = wsbuf + ((size_t)curLv * N_POINTS + base + p*256) * 2;
                    atomicAdd(w,     a0[p]);
                    atomicAdd(w + 1, a1[p]);
                }
            }
            curLv = lv;
            #pragma unroll
            for (int p = 0; p < 8; ++p) { a0[p] = 0.0f; a1[p] = 0.0f; }
        }

        const float r = args.r[lv];
        const uint32_t ncMul = args.ncMul[lv];
        const float* __restrict__ tab =
            tables + (size_t)lv * ((size_t)TABLE_SIZE * 2);

        float2 tA0, tA1, tA2, tA3, tA4, tA5, tA6, tA7;
        float2 tB0, tB1, tB2, tB3, tB4, tB5, tB6, tB7;
        float wcA[8], wcB[8];

        // 2-deep software pipeline: 8-16 loads in flight per wave
        ISSUE(A, 0)
        ISSUE(B, 1) WAIT(A, 8) FMA8(A, 0)
        ISSUE(A, 2) WAIT(B, 8) FMA8(B, 1)
        ISSUE(B, 3) WAIT(A, 8) FMA8(A, 2)
        ISSUE(A, 4) WAIT(B, 8) FMA8(B, 3)
        ISSUE(B, 5) WAIT(A, 8) FMA8(A, 4)
        ISSUE(A, 6) WAIT(B, 8) FMA8(B, 5)
        ISSUE(B, 7) WAIT(A, 8) FMA8(A, 6)
                    WAIT(B, 0) FMA8(B, 7)
    }

    if (curLv >= 0) {
        #pragma unroll
        for (int p = 0; p < 8; ++p) {
            float* w = wsbuf + ((size_t)curLv * N_POINTS + base + p*256) * 2;
            atomicAdd(w,     a0[p]);
            atomicAdd(w + 1, a1[p]);
        }
    }
}

// ---- phase 2: transpose ws[l][n] -> out[n][l] ------------------------------
__global__ __launch_bounds__(256) void hash_embed_phase2(
    const float2* __restrict__ ws,
    float2* __restrict__ out)
{
    __shared__ float2 tile[64][NUM_LEVELS + 1];
    const int n0 = blockIdx.x * 64;
    const int t = threadIdx.x;
    #pragma unroll
    for (int k = 0; k < 4; ++k) {
        const int e = k * 256 + t;
        const int l = e >> 6;
        const int j = e & 63;
        tile[j][l] = ws[(size_t)l * N_POINTS + n0 + j];
    }
    __syncthreads();
    #pragma unroll
    for (int k = 0; k < 4; ++k) {
        const int e = k * 256 + t;
        const int nl = e >> 4;
        const int l = e & 15;
        out[(size_t)(n0 + nl) * NUM_LEVELS + l] = tile[nl][l];
    }
}

// ---- fallback (R1-proven): interleaved levels, direct out ------------------
__global__ __launch_bounds__(256) void hash_embed_direct(
    const float* __restrict__ x,
    const float* __restrict__ tables,
    float* __restrict__ out,
    Args args)
{
    const int t = blockIdx.x * blockDim.x + threadIdx.x;
    const int n = t >> 4;
    const int l = t & 15;
    if (n >= N_POINTS) return;

    const float px = x[n * 3 + 0];
    const float py = x[n * 3 + 1];
    const float pz = x[n * 3 + 2];
    const float nx = fminf(fmaxf((px + 2.0f) * 0.25f, 0.0f), 1.0f);
    const float ny = fminf(fmaxf((py + 2.0f) * 0.25f, 0.0f), 1.0f);
    const float nz = fminf(fmaxf((pz + 2.0f) * 0.25f, 0.0f), 1.0f);

    const float r = args.r[l];
    const float sx = nx * r, sy = ny * r, sz = nz * r;
    const float fx = floorf(sx), fy = floorf(sy), fz = floorf(sz);
    const float wxv = sx - fx, wyv = sy - fy, wzv = sz - fz;

    const uint32_t hx0 = (uint32_t)(int)fx * PX;
    const uint32_t hy0 = (uint32_t)(int)fy * PY;
    const uint32_t hz0 = (uint32_t)(int)fz * PZ;
    const uint32_t hx1 = hx0 + PX, hy1 = hy0 + PY, hz1 = hz0 + PZ;

    const float ax = 1.0f - wxv, ay = 1.0f - wyv, az = 1.0f - wzv;
    const float* __restrict__ tab = tables + (size_t)l * ((size_t)TABLE_SIZE * 2);

    float f0 = 0.0f, f1 = 0.0f;
    #pragma unroll
    for (int c = 0; c < 8; ++c) {
        const uint32_t hh = ((c & 4) ? hx1 : hx0) ^ ((c & 2) ? hy1 : hy0)
                          ^ ((c & 1) ? hz1 : hz0);
        const uint32_t idx = hh & HASH_MASK;
        const float2 emb = *reinterpret_cast<const float2*>(tab + (size_t)idx * 2);
        const float w = (((c & 4) ? wxv : ax) * ((c & 2) ? wyv : ay)) * ((c & 1) ? wzv : az);
        f0 = fmaf(w, emb.x, f0);
        f1 = fmaf(w, emb.y, f1);
    }
    float2* o = reinterpret_cast<float2*>(out + (size_t)n * (NUM_LEVELS * 2) + l * 2);
    *o = make_float2(f0, f1);
}

extern "C" void kernel_launch(void* const* d_in, const int* in_sizes, int n_in,
                              void* d_out, int out_size, void* d_ws, size_t ws_size,
                              hipStream_t stream) {
    const float* x      = (const float*)d_in[0];
    const float* tables = (const float*)d_in[1];
    float* out          = (float*)d_out;

    Args args;
    memset(&args, 0, sizeof(args));
    const double b = exp((log(2048.0) - log(16.0)) / 15.0);
    int nc[NUM_LEVELS];
    for (int i = 0; i < NUM_LEVELS; ++i) {
        const double ri = floor(16.0 * pow(b, (double)i));
        args.r[i] = (float)ri;
        // accessed-footprint model: E distinct corners hash-spread over 2^21
        // slots, 8 entries per 64B line
        double E = (ri + 1.0) * (ri + 1.0) * (ri + 1.0);
        if (E > 1.8e6) E = 1.8e6;
        const double lines = 262144.0 * (1.0 - exp(-8.0 * E / 2097152.0));
        const double bytes = lines * 64.0;
        int n = (bytes <= 2.5e6) ? 1 : (int)ceil(bytes / 2.8e6);
        if (n < 1) n = 1;
        if (n > 8) n = 8;
        nc[i] = n;
        args.ncMul[i] = (uint32_t)n;
    }

    // build unit list (level-major) and balanced slot partition
    uint32_t allUnits[MAX_UNITS];
    int total = 0;
    for (int l = 0; l < NUM_LEVELS; ++l) {
        for (int c = 0; c < nc[l]; ++c) {
            const uint32_t cstart =
                (uint32_t)((((unsigned long long)c << 21) + (unsigned)nc[l] - 1)
                           / (unsigned)nc[l]);
            allUnits[total++] = ((uint32_t)l << 27) | ((uint32_t)c << 24) | cstart;
        }
    }
    const int qn = total / 8, rm = total % 8;
    int off = 0;
    for (int s = 0; s < 8; ++s) {
        args.slotStart[s] = off;
        off += qn + (s < rm ? 1 : 0);
    }
    args.slotStart[8] = off;   // == total
    for (int i = 0; i < total; ++i) args.units[i] = allUnits[i];

    const size_t ws_needed = (size_t)NUM_LEVELS * N_POINTS * sizeof(float2); // 32 MB
    if (ws_size >= ws_needed) {
        float* wsbuf = (float*)d_ws;
        hipMemsetAsync(d_ws, 0, ws_needed, stream);
        hipLaunchKernelGGL(hash_embed_phase1_v15, dim3(GRID_P1), dim3(256),
                           0, stream, x, tables, wsbuf, args);
        hipLaunchKernelGGL(hash_embed_phase2, dim3(N_POINTS / 64), dim3(256),
                           0, stream, (const float2*)wsbuf, (float2*)out);
    } else {
        const int totalThreads = N_POINTS * NUM_LEVELS;
        hipLaunchKernelGGL(hash_embed_direct, dim3((totalThreads + 255) / 256), dim3(256),
                           0, stream, x, tables, out, args);
    }
}

// Round 16
// 229.066 us; speedup vs baseline: 4.6713x; 2.0153x over previous
//
#include <hip/hip_runtime.h>
#include <math.h>

#define NUM_LEVELS 16
#define LOG2_T 21
#define TABLE_SIZE (1u << LOG2_T)
#define HASH_MASK (TABLE_SIZE - 1u)
#define N_POINTS 262144
#define GRID_P1 1024           // 128 slices x 8 xcd-slots; 4 blocks/CU co-resident
#define PTS_PER_BLOCK 2048     // 8 pts/thread x 256 threads
#define PX 73856093u
#define PY 19349663u
#define PZ 83492791u

struct Args { float r[NUM_LEVELS]; int l2nc[NUM_LEVELS]; };

// two-level paste so trailing digit doesn't fuse with ".x" into one pp-token
#define CAT3_(a, b, c) a##b##c
#define TREG(SET, i) CAT3_(t, SET, i)

// Issue 8 corner loads for point p into register set SET; weights in wc##SET.
// Recomputes floor/frac/hash from persistent nx/ny/nz (keeps live state small).
#define CORNER(SET, i)                                                        \
    {                                                                         \
        const uint32_t h = (((i) & 4) ? X1 : X0) ^ (((i) & 2) ? Y1 : Y0)      \
                         ^ (((i) & 1) ? Z1 : Z0);                             \
        const uint32_t idx = h & HASH_MASK;                                   \
        const bool m = (idx >> shift) == (uint32_t)c;                         \
        const uint32_t off = m ? (idx << 3) : dummy_off;                      \
        wc##SET[i] = m ? (((((i) & 4) ? qx : axq) * (((i) & 2) ? qy : ayq))   \
                          * (((i) & 1) ? qz : azq))                           \
                       : 0.0f;                                                \
        asm volatile("global_load_dwordx2 %0, %1, %2"                         \
                     : "=v"(TREG(SET, i)) : "v"(off), "s"(tab));              \
    }

#define ISSUE(SET, p)                                                         \
    {                                                                         \
        const float sx = nxx[p] * r, sy = nyy[p] * r, sz = nzz[p] * r;        \
        const float fx = floorf(sx), fy = floorf(sy), fz = floorf(sz);        \
        const float qx = sx - fx, qy = sy - fy, qz = sz - fz;                 \
        const float axq = 1.0f - qx, ayq = 1.0f - qy, azq = 1.0f - qz;        \
        const uint32_t X0 = (uint32_t)(int)fx * PX;                           \
        const uint32_t Y0 = (uint32_t)(int)fy * PY;                           \
        const uint32_t Z0 = (uint32_t)(int)fz * PZ;                           \
        const uint32_t X1 = X0 + PX, Y1 = Y0 + PY, Z1 = Z0 + PZ;              \
        CORNER(SET, 0) CORNER(SET, 1) CORNER(SET, 2) CORNER(SET, 3)           \
        CORNER(SET, 4) CORNER(SET, 5) CORNER(SET, 6) CORNER(SET, 7)           \
    }

#define WAIT(SET, CNT)                                                        \
    asm volatile("s_waitcnt vmcnt(" #CNT ")"                                  \
                 : "+v"(TREG(SET, 0)), "+v"(TREG(SET, 1)),                    \
                   "+v"(TREG(SET, 2)), "+v"(TREG(SET, 3)),                    \
                   "+v"(TREG(SET, 4)), "+v"(TREG(SET, 5)),                    \
                   "+v"(TREG(SET, 6)), "+v"(TREG(SET, 7)));

#define FMA2(SET, p, i)                                                       \
    a0[p] = fmaf(wc##SET[i], TREG(SET, i).x, a0[p]);                          \
    a1[p] = fmaf(wc##SET[i], TREG(SET, i).y, a1[p]);

#define FMA8(SET, p)                                                          \
    FMA2(SET, p, 0) FMA2(SET, p, 1) FMA2(SET, p, 2) FMA2(SET, p, 3)           \
    FMA2(SET, p, 4) FMA2(SET, p, 5) FMA2(SET, p, 6) FMA2(SET, p, 7)

// ---- phase 1: co-resident cohort, XCD-pinned levels, L2 chunks, 2-deep pipe
__global__ __launch_bounds__(256) void hash_embed_phase1_v12(
    const float* __restrict__ x,
    const float* __restrict__ tables,
    float2* __restrict__ wsbuf,       // [NUM_LEVELS][N_POINTS]
    Args args)
{
    const int bid = blockIdx.x;
    const int slot = bid & 7;          // dispatch-order XCD heuristic (perf-only)
    const int slice = bid >> 3;        // 0..127
    const int base = slice * PTS_PER_BLOCK + threadIdx.x;

    // persistent across BOTH levels: clamped normalized coords (x read once)
    float nxx[8], nyy[8], nzz[8];
    #pragma unroll
    for (int p = 0; p < 8; ++p) {
        const int n = base + p * 256;
        const float px = x[n * 3 + 0];
        const float py = x[n * 3 + 1];
        const float pz = x[n * 3 + 2];
        nxx[p] = fminf(fmaxf((px + 2.0f) * 0.25f, 0.0f), 1.0f);
        nyy[p] = fminf(fmaxf((py + 2.0f) * 0.25f, 0.0f), 1.0f);
        nzz[p] = fminf(fmaxf((pz + 2.0f) * 0.25f, 0.0f), 1.0f);
    }

    #pragma unroll 1
    for (int li = 0; li < 2; ++li) {
        const int lv = (li == 0) ? slot : 15 - slot;
        const float r = args.r[lv];
        const int l2nc = args.l2nc[lv];
        const int shift = LOG2_T - l2nc;
        const int nc = 1 << l2nc;
        const float* __restrict__ tab =
            tables + (size_t)lv * ((size_t)TABLE_SIZE * 2);

        float a0[8], a1[8];
        #pragma unroll
        for (int p = 0; p < 8; ++p) { a0[p] = 0.0f; a1[p] = 0.0f; }

        #pragma unroll 1
        for (int c = 0; c < nc; ++c) {
            const uint32_t dummy_off = ((uint32_t)c << shift) << 3;  // in-chunk line
            float2 tA0, tA1, tA2, tA3, tA4, tA5, tA6, tA7;
            float2 tB0, tB1, tB2, tB3, tB4, tB5, tB6, tB7;
            float wcA[8], wcB[8];

            // 2-deep software pipeline: 8-16 loads in flight per wave
            ISSUE(A, 0)
            ISSUE(B, 1) WAIT(A, 8) FMA8(A, 0)
            ISSUE(A, 2) WAIT(B, 8) FMA8(B, 1)
            ISSUE(B, 3) WAIT(A, 8) FMA8(A, 2)
            ISSUE(A, 4) WAIT(B, 8) FMA8(B, 3)
            ISSUE(B, 5) WAIT(A, 8) FMA8(A, 4)
            ISSUE(A, 6) WAIT(B, 8) FMA8(B, 5)
            ISSUE(B, 7) WAIT(A, 8) FMA8(A, 6)
                        WAIT(B, 0) FMA8(B, 7)
        }

        #pragma unroll
        for (int p = 0; p < 8; ++p) {
            wsbuf[(size_t)lv * N_POINTS + base + p * 256] = make_float2(a0[p], a1[p]);
        }
    }
}

// ---- phase 2: transpose ws[l][n] -> out[n][l] ------------------------------
__global__ __launch_bounds__(256) void hash_embed_phase2(
    const float2* __restrict__ ws,
    float2* __restrict__ out)
{
    __shared__ float2 tile[64][NUM_LEVELS + 1];
    const int n0 = blockIdx.x * 64;
    const int t = threadIdx.x;
    #pragma unroll
    for (int k = 0; k < 4; ++k) {
        const int e = k * 256 + t;
        const int l = e >> 6;
        const int j = e & 63;
        tile[j][l] = ws[(size_t)l * N_POINTS + n0 + j];
    }
    __syncthreads();
    #pragma unroll
    for (int k = 0; k < 4; ++k) {
        const int e = k * 256 + t;
        const int nl = e >> 4;
        const int l = e & 15;
        out[(size_t)(n0 + nl) * NUM_LEVELS + l] = tile[nl][l];
    }
}

// ---- fallback (R1-proven): interleaved levels, direct out ------------------
__global__ __launch_bounds__(256) void hash_embed_direct(
    const float* __restrict__ x,
    const float* __restrict__ tables,
    float* __restrict__ out,
    Args args)
{
    const int t = blockIdx.x * blockDim.x + threadIdx.x;
    const int n = t >> 4;
    const int l = t & 15;
    if (n >= N_POINTS) return;

    const float px = x[n * 3 + 0];
    const float py = x[n * 3 + 1];
    const float pz = x[n * 3 + 2];
    const float nx = fminf(fmaxf((px + 2.0f) * 0.25f, 0.0f), 1.0f);
    const float ny = fminf(fmaxf((py + 2.0f) * 0.25f, 0.0f), 1.0f);
    const float nz = fminf(fmaxf((pz + 2.0f) * 0.25f, 0.0f), 1.0f);

    const float r = args.r[l];
    const float sx = nx * r, sy = ny * r, sz = nz * r;
    const float fx = floorf(sx), fy = floorf(sy), fz = floorf(sz);
    const float wxv = sx - fx, wyv = sy - fy, wzv = sz - fz;

    const uint32_t hx0 = (uint32_t)(int)fx * PX;
    const uint32_t hy0 = (uint32_t)(int)fy * PY;
    const uint32_t hz0 = (uint32_t)(int)fz * PZ;
    const uint32_t hx1 = hx0 + PX, hy1 = hy0 + PY, hz1 = hz0 + PZ;

    const float ax = 1.0f - wxv, ay = 1.0f - wyv, az = 1.0f - wzv;
    const float* __restrict__ tab = tables + (size_t)l * ((size_t)TABLE_SIZE * 2);

    float f0 = 0.0f, f1 = 0.0f;
    #pragma unroll
    for (int c = 0; c < 8; ++c) {
        const uint32_t hh = ((c & 4) ? hx1 : hx0) ^ ((c & 2) ? hy1 : hy0)
                          ^ ((c & 1) ? hz1 : hz0);
        const uint32_t idx = hh & HASH_MASK;
        const float2 emb = *reinterpret_cast<const float2*>(tab + (size_t)idx * 2);
        const float w = (((c & 4) ? wxv : ax) * ((c & 2) ? wyv : ay)) * ((c & 1) ? wzv : az);
        f0 = fmaf(w, emb.x, f0);
        f1 = fmaf(w, emb.y, f1);
    }
    float2* o = reinterpret_cast<float2*>(out + (size_t)n * (NUM_LEVELS * 2) + l * 2);
    *o = make_float2(f0, f1);
}

extern "C" void kernel_launch(void* const* d_in, const int* in_sizes, int n_in,
                              void* d_out, int out_size, void* d_ws, size_t ws_size,
                              hipStream_t stream) {
    const float* x      = (const float*)d_in[0];
    const float* tables = (const float*)d_in[1];
    float* out          = (float*)d_out;

    Args args;
    const double b = exp((log(2048.0) - log(16.0)) / 15.0);
    for (int i = 0; i < NUM_LEVELS; ++i) {
        const double ri = floor(16.0 * pow(b, (double)i));
        args.r[i] = (float)ri;
        // accessed-footprint model: E distinct corners hash-spread over 2^21
        // slots, 8 entries per 64B line
        double E = (ri + 1.0) * (ri + 1.0) * (ri + 1.0);
        if (E > 1.8e6) E = 1.8e6;
        const double lines = 262144.0 * (1.0 - exp(-8.0 * E / 2097152.0));
        const double bytes = lines * 64.0;
        // chunk so each chunk's footprint fits L2 (~3.7 MB target), max nc=8
        int l2 = 0;
        while (l2 < 3 && bytes / (double)(1 << l2) > 3.7e6) ++l2;
        args.l2nc[i] = l2;
    }

    const size_t ws_needed = (size_t)NUM_LEVELS * N_POINTS * sizeof(float2); // 32 MB
    if (ws_size >= ws_needed) {
        float2* wsbuf = (float2*)d_ws;
        hipLaunchKernelGGL(hash_embed_phase1_v12, dim3(GRID_P1), dim3(256),
                           0, stream, x, tables, wsbuf, args);
        hipLaunchKernelGGL(hash_embed_phase2, dim3(N_POINTS / 64), dim3(256),
                           0, stream, wsbuf, (float2*)out);
    } else {
        const int total = N_POINTS * NUM_LEVELS;
        hipLaunchKernelGGL(hash_embed_direct, dim3((total + 255) / 256), dim3(256),
                           0, stream, x, tables, out, args);
    }
}